// Round 3
// baseline (241.681 us; speedup 1.0000x reference)
//
#include <hip/hip_runtime.h>
#include <math.h>

// Problem constants (B=8 batches, N=M=2048 points, D=3)
#define BATCH 8
#define NPTS 2048
#define THREADS 256
#define HALF_COLS 1024         // columns staged per LDS stage
#define TILES_H 32             // 32-col MFMA tiles per staged half
#define CROWS 128              // classic kernel: 4 row-groups of 32
#define MROWS 64               // merged kernel: 2 row-groups x 2 col-splits
#define LOG_M 7.62559580411076 // ln(2048)

typedef __attribute__((ext_vector_type(8)))  __bf16 bf16x8;
typedef __attribute__((ext_vector_type(16))) float  f32x16;
typedef __attribute__((ext_vector_type(2)))  float  f32x2;

union FragU { unsigned short u[8]; uint4 v; };

__device__ __forceinline__ unsigned short f2bf(float f) {
    union { float f; unsigned u; } x; x.f = f;
    unsigned r = x.u + 0x7FFFu + ((x.u >> 16) & 1u);   // RNE
    return (unsigned short)(r >> 16);
}
__device__ __forceinline__ float bf2f(unsigned short b) {
    union { unsigned u; float f; } x; x.u = ((unsigned)b) << 16;
    return x.f;
}

// Single-pass softmin via 32x32x16 MFMA with estimated LSE shift (no max pass).
//   E_ij = 2^( sigma*(x.y + pot_j - ysq_j) + (old_i - rowconst_i)/k2 )
//        = exp((f_i + g_j - C_ij)/eps) / M            (exact identity)
// Row sums give ft_i = old_i - k2*log2(rowsum)  (production-verified).
// NEW (r20): col sums of the SAME E give the transposed update exactly:
//   gt_j = g_j - k2*log2(colsum_j)   [derived with identical constants]
// so the g_ab plane is deleted on interior launches: the merged xy plane
// accumulates col sums (LDS CS[] per half -> global atomic R), and the NEXT
// launch's readers finalize g = g_old - 0.5*k2_prev*log2(R) on the fly
// (writer block persists it into a ping-pong G buffer to keep the chain O(1)).
// Falsification record:
//  r7  launch_bounds(512,4) pipeline: scratch spill
//  r10 poly-exp2 on VALU: v_exp_f32 blocks SIMD issue ~16cyc; no better
//  r11/r12 single-kernel fusion: grid-barrier cost >> 3us launch gaps
//  r13 triangle/mirror transpose: mirror scatter + imbalance ate the win
//      (r20 keeps only the cheap half: col sums, no mirror, uniform blocks)
//  r15 32-row blocks: staging doubles, barriers 4x
//  r17 manual MFMA->exp2 pipeline: defeats compiler scheduling
//  r18 (WIN -5.6us): v_pk_add_f32 + transposed-LDS-spill reduction
//  r19 (WIN -24.7us): 128-row blocks halve staging+ramp; ysq folded in CF1.y
// Balance note (the r13 lesson): interior launches use UNIFORM 64-row blocks,
// grid (32,8,3)=768 at 2 blocks/CU -> 512 resident + 256 backfill, so the
// 25% work cut converts to makespan instead of idling half the CUs.
// A/B layout: m(n)=lane&31, k=(lane>>5)*8+j.
// C/D layout (verified m74/m101): col=lane&31, row=(reg&3)+8*(reg>>2)+4*(lane>>5).

// ---------------- classic 4-plane kernel (launches 0 and 9) ----------------
__global__ __launch_bounds__(THREADS, 2) void softmin_classic(
    const float* __restrict__ x, const float* __restrict__ y,
    const float* __restrict__ potSrc, float* __restrict__ potDst,
    uint4* __restrict__ CF0, uint2* __restrict__ CF1,
    const float* __restrict__ gPrev, const float* __restrict__ rPrev,
    float* __restrict__ gDst, float* __restrict__ zeroR,
    float sigma, float k2, float inv_k2, float rowc0, float prevHalfK2,
    int avg, int first, int last, float* __restrict__ out)
{
    __shared__ uint4 BF[TILES_H][64];     // 32 KB: B frags (one half), slot=lane
    __shared__ uint4 AF[4][64];           //  4 KB: A frags (4 row-groups)
    __shared__ float NM[CROWS];           // -m2_hat per row; res stash on last

    const int type  = blockIdx.z;
    const int batch = blockIdx.y;

    if (zeroR) {   // L0: zero the R buffer launch 1 will accumulate into
        const int lid = ((blockIdx.z * gridDim.y + blockIdx.y) * gridDim.x + blockIdx.x);
        if (threadIdx.x < 32) zeroR[lid * 32 + threadIdx.x] = 0.0f;
    }

    const float* rowP;
    const float* colP;
    int hslot, oslot, cs;
    if (type == 0)      { rowP = x; colP = y; hslot = 1; oslot = 0; cs = 1; }  // f_ba
    else if (type == 1) { rowP = y; colP = x; hslot = 0; oslot = 1; cs = 0; }  // g_ab
    else if (type == 2) { rowP = x; colP = x; hslot = 2; oslot = 2; cs = 0; }  // f_aa
    else                { rowP = y; colP = y; hslot = 3; oslot = 3; cs = 1; }  // g_bb

    rowP += batch * NPTS * 3;
    colP += batch * NPTS * 3;
    const float* hP   = potSrc + (hslot * BATCH + batch) * NPTS;
    const float* oldP = potSrc + (oslot * BATCH + batch) * NPTS;
    float*       outP = potDst + (oslot * BATCH + batch) * NPTS;
    const size_t cbase = ((size_t)cs * BATCH + batch) * NPTS;

    // L9: potSrc slot 1 (g_ab) is stale; finalize from G chain + raw colsums.
    const bool  fixH = (rPrev != nullptr) && (hslot == 1);
    const bool  fixO = (rPrev != nullptr) && (oslot == 1);
    const float* gB  = gPrev + batch * NPTS;
    const float* rB  = rPrev + batch * NPTS;
    float* gW = (gDst != nullptr && oslot == 1) ? (gDst + batch * NPTS) : nullptr;

    // ---- stage A fragments: 4 groups x 64 slots = all 256 threads ----
    {
        const int gg = threadIdx.x >> 6, idx = threadIdx.x & 63;
        const int row = blockIdx.x * CROWS + gg * 32 + (idx & 31);
        float x0 = rowP[3 * row + 0], x1 = rowP[3 * row + 1], x2 = rowP[3 * row + 2];
        float p0 = sigma * (x0 - 0.5f), p1 = sigma * (x1 - 0.5f), p2 = sigma * (x2 - 0.5f);
        unsigned short h0 = f2bf(p0); unsigned short l0 = f2bf(p0 - bf2f(h0));
        unsigned short h1 = f2bf(p1); unsigned short l1 = f2bf(p1 - bf2f(h1));
        unsigned short h2 = f2bf(p2); unsigned short l2 = f2bf(p2 - bf2f(h2));
        FragU f;
        if (idx < 32) {   // k0-7: dim0 (xh,xh,xl,xl), dim1 (xh,xh,xl,xl)
            f.u[0] = h0; f.u[1] = h0; f.u[2] = l0; f.u[3] = l0;
            f.u[4] = h1; f.u[5] = h1; f.u[6] = l1; f.u[7] = l1;
        } else {          // k8-15: dim2 (xh,xh,xl,xl), 1,1,1, 0
            f.u[0] = h2; f.u[1] = h2; f.u[2] = l2; f.u[3] = l2;
            f.u[4] = 0x3F80; f.u[5] = 0x3F80; f.u[6] = 0x3F80; f.u[7] = 0;
        }
        AF[gg][idx] = f.v;
    }
    if (threadIdx.x < CROWS) {
        const int r = threadIdx.x;
        const int i = blockIdx.x * CROWS + r;
        float x0 = rowP[3 * i + 0], x1 = rowP[3 * i + 1], x2 = rowP[3 * i + 2];
        float p0 = x0 - 0.5f, p1 = x1 - 0.5f, p2 = x2 - 0.5f;
        float rowconst = 0.5f * (p0 * p0 + p1 * p1 + p2 * p2) + rowc0;
        float oldv = first ? 0.0f
                   : (fixO ? (gB[i] - prevHalfK2 * __log2f(rB[i])) : oldP[i]);
        NM[r] = (oldv - rowconst) * inv_k2;
    }

    const int lane = threadIdx.x & 63;
    const int g    = threadIdx.x >> 6;   // wave index == row-group 0..3
    const int khalf = lane >> 5;

    f32x2 sp[8];
    #pragma unroll
    for (int q = 0; q < 8; ++q) { sp[q].x = 0.0f; sp[q].y = 0.0f; }
    bf16x8 af;
    f32x16 nmv;

    for (int h = 0; h < 2; ++h) {
        if (h) __syncthreads();

        if (first) {
            const int writer = (blockIdx.x == 0) && (type <= 1);
            for (int jj = threadIdx.x; jj < HALF_COLS; jj += THREADS) {
                const int j = h * HALF_COLS + jj;
                float y0 = colP[3 * j + 0], y1 = colP[3 * j + 1], y2 = colP[3 * j + 2];
                float p0 = y0 - 0.5f, p1 = y1 - 0.5f, p2 = y2 - 0.5f;
                unsigned short h0 = f2bf(p0); unsigned short l0 = f2bf(p0 - bf2f(h0));
                unsigned short h1 = f2bf(p1); unsigned short l1 = f2bf(p1 - bf2f(h1));
                unsigned short h2 = f2bf(p2); unsigned short l2 = f2bf(p2 - bf2f(h2));
                float ysq = 0.5f * (p0 * p0 + p1 * p1 + p2 * p2);
                float hhe = -sigma * ysq;                    // pot == 0
                unsigned short hA = f2bf(hhe); float r1 = hhe - bf2f(hA);
                unsigned short hB = f2bf(r1);  float r2 = r1 - bf2f(hB);
                unsigned short hC = f2bf(r2);
                FragU f0, f1;
                f0.u[0] = h0; f0.u[1] = l0; f0.u[2] = h0; f0.u[3] = l0;
                f0.u[4] = h1; f0.u[5] = l1; f0.u[6] = h1; f0.u[7] = l1;
                f1.u[0] = h2; f1.u[1] = l2; f1.u[2] = h2; f1.u[3] = l2;
                f1.u[4] = hA; f1.u[5] = hB; f1.u[6] = hC; f1.u[7] = 0;
                BF[jj >> 5][jj & 31]        = f0.v;
                BF[jj >> 5][32 + (jj & 31)] = f1.v;
                if (writer) {
                    CF0[cbase + j] = f0.v;
                    CF1[cbase + j] = make_uint2(f1.v.x, __float_as_uint(ysq));
                }
            }
        } else {
            for (int jj = threadIdx.x; jj < HALF_COLS; jj += THREADS) {
                const int j = h * HALF_COLS + jj;
                uint4 f0  = CF0[cbase + j];
                uint2 f1l = CF1[cbase + j];
                float ysq = __uint_as_float(f1l.y);
                float hpj = fixH ? (gB[j] - prevHalfK2 * __log2f(rB[j])) : hP[j];
                float hhe = sigma * (hpj - ysq);
                unsigned short hA = f2bf(hhe); float r1 = hhe - bf2f(hA);
                unsigned short hB = f2bf(r1);  float r2 = r1 - bf2f(hB);
                unsigned short hC = f2bf(r2);
                uint4 f1 = make_uint4(f1l.x, f1l.x,
                                      (unsigned)hA | ((unsigned)hB << 16),
                                      (unsigned)hC);
                BF[jj >> 5][jj & 31]        = f0;
                BF[jj >> 5][32 + (jj & 31)] = f1;
            }
        }
        __syncthreads();

        if (h == 0) {
            af = *(const bf16x8*)&AF[g][lane];
            #pragma unroll
            for (int r = 0; r < 16; ++r) {
                const int row = (r & 3) + 8 * (r >> 2) + 4 * khalf;
                nmv[r] = NM[g * 32 + row];
            }
        }

        #pragma unroll 2
        for (int t = 0; t < TILES_H; ++t) {
            bf16x8 bf = *(const bf16x8*)&BF[t][lane];
            f32x16 acc = __builtin_amdgcn_mfma_f32_32x32x16_bf16(af, bf, nmv, 0, 0, 0);
            #pragma unroll
            for (int q = 0; q < 8; ++q) {
                f32x2 e;
                e.x = __builtin_amdgcn_exp2f(acc[2 * q]);
                e.y = __builtin_amdgcn_exp2f(acc[2 * q + 1]);
                asm("v_pk_add_f32 %0, %0, %1" : "+v"(sp[q]) : "v"(e));
            }
        }
    }

    // ---- transposed reduction via spill into dead BF space ----
    __syncthreads();
    {
        f32x2* SP = (f32x2*)&BF[0][0];
        #pragma unroll
        for (int q = 0; q < 8; ++q)
            SP[(q * 4 + g) * 64 + (lane ^ ((q & 3) << 3))] = sp[q];
    }
    __syncthreads();

    {
        const float* SPf = (const float*)&BF[0][0];
        const int v  = threadIdx.x >> 1;        // row 0..127
        const int p  = threadIdx.x & 1;
        const int gg = v >> 5, vv = v & 31;
        const int kh = (vv >> 2) & 1;
        const int r  = (vv & 3) | ((vv >> 3) << 2);
        const int q  = r >> 1, comp = r & 1;
        const int sw = (q & 3) << 3;
        float val = 0.0f;
        #pragma unroll
        for (int jj = 0; jj < 16; ++jj) {
            const int j = (p * 16 + jj + v) & 31;
            const int l = kh * 32 + j;
            val += SPf[(((q * 4 + gg) * 64) + (l ^ sw)) * 2 + comp];
        }
        val += __shfl_xor(val, 1, 64);
        if (p == 0) {
            const int i = blockIdx.x * CROWS + v;
            float oldv = first ? 0.0f
                       : (fixO ? (gB[i] - prevHalfK2 * __log2f(rB[i])) : oldP[i]);
            float res  = oldv - k2 * __log2f(val);
            outP[i] = avg ? 0.5f * (oldv + res) : res;
            if (gW) gW[i] = res;     // L0: seed G0 with g_0
            if (last) NM[v] = res;
        }
    }

    if (last) {
        __syncthreads();
        if (g == 0) {
            float v2 = NM[lane] + NM[64 + lane];
            #pragma unroll
            for (int off = 32; off >= 1; off >>= 1)
                v2 += __shfl_xor(v2, off, 64);
            if (lane == 0) {
                float sign = (type >= 2) ? -1.0f : 1.0f;
                atomicAdd(out + batch, sign * v2 * (1.0f / NPTS));
            }
        }
    }
}

// -------- merged 3-plane kernel (launches 1..8): z=0 xy(+colsum), 1 xx, 2 yy
__global__ __launch_bounds__(THREADS, 2) void softmin_merged(
    const float* __restrict__ x, const float* __restrict__ y,
    const float* __restrict__ potSrc, float* __restrict__ potDst,
    const uint4* __restrict__ CF0, const uint2* __restrict__ CF1,
    const float* __restrict__ gPrev, const float* __restrict__ rPrev,
    float* __restrict__ gDst, float* __restrict__ rCur, float* __restrict__ rZero,
    float sigma, float k2, float inv_k2, float rowc0, float prevHalfK2)
{
    __shared__ uint4 BF[TILES_H][64];     // 32 KB
    __shared__ uint4 AF[2][64];           //  2 KB
    __shared__ float NM[MROWS];
    __shared__ float CS[HALF_COLS];       //  4 KB col partials (z=0 only)

    const int type  = blockIdx.z;
    const int batch = blockIdx.y;
    const int doCol = (type == 0);

    const float* rowP; const float* colP;
    int oslot, hslot, cs;
    if (type == 0)      { rowP = x; colP = y; oslot = 0; hslot = 0; cs = 1; }  // xy merged
    else if (type == 1) { rowP = x; colP = x; oslot = 2; hslot = 2; cs = 0; }  // f_aa
    else                { rowP = y; colP = y; oslot = 3; hslot = 3; cs = 1; }  // g_bb

    rowP += batch * NPTS * 3;
    colP += batch * NPTS * 3;
    const float* hP   = potSrc + (hslot * BATCH + batch) * NPTS;  // unused z=0
    const float* oldP = potSrc + (oslot * BATCH + batch) * NPTS;
    float*       outP = potDst + (oslot * BATCH + batch) * NPTS;
    const size_t cbase = ((size_t)cs * BATCH + batch) * NPTS;
    const int gb = batch * NPTS;
    const int writer = doCol && (blockIdx.x == 0);

    if (doCol) {
        for (int c0 = threadIdx.x; c0 < HALF_COLS; c0 += THREADS) CS[c0] = 0.0f;
        const int zb = (batch * 32 + blockIdx.x) * 64;   // zero next launch's R
        if (threadIdx.x < 64) rZero[zb + threadIdx.x] = 0.0f;
    }

    // ---- A fragments (2 groups) + NM ----
    if (threadIdx.x < 128) {
        const int gg = threadIdx.x >> 6, idx = threadIdx.x & 63;
        const int row = blockIdx.x * MROWS + gg * 32 + (idx & 31);
        float x0 = rowP[3 * row + 0], x1 = rowP[3 * row + 1], x2 = rowP[3 * row + 2];
        float p0 = sigma * (x0 - 0.5f), p1 = sigma * (x1 - 0.5f), p2 = sigma * (x2 - 0.5f);
        unsigned short h0 = f2bf(p0); unsigned short l0 = f2bf(p0 - bf2f(h0));
        unsigned short h1 = f2bf(p1); unsigned short l1 = f2bf(p1 - bf2f(h1));
        unsigned short h2 = f2bf(p2); unsigned short l2 = f2bf(p2 - bf2f(h2));
        FragU f;
        if (idx < 32) {
            f.u[0] = h0; f.u[1] = h0; f.u[2] = l0; f.u[3] = l0;
            f.u[4] = h1; f.u[5] = h1; f.u[6] = l1; f.u[7] = l1;
        } else {
            f.u[0] = h2; f.u[1] = h2; f.u[2] = l2; f.u[3] = l2;
            f.u[4] = 0x3F80; f.u[5] = 0x3F80; f.u[6] = 0x3F80; f.u[7] = 0;
        }
        AF[gg][idx] = f.v;
    } else if (threadIdx.x < 128 + MROWS) {
        const int r = threadIdx.x - 128;
        const int i = blockIdx.x * MROWS + r;
        float x0 = rowP[3 * i + 0], x1 = rowP[3 * i + 1], x2 = rowP[3 * i + 2];
        float p0 = x0 - 0.5f, p1 = x1 - 0.5f, p2 = x2 - 0.5f;
        float rowconst = 0.5f * (p0 * p0 + p1 * p1 + p2 * p2) + rowc0;
        NM[r] = (oldP[i] - rowconst) * inv_k2;
    }

    const int lane = threadIdx.x & 63;
    const int wave = threadIdx.x >> 6;
    const int g    = wave >> 1;        // row-group 0..1
    const int c    = wave & 1;         // col-split 0..1
    const int khalf = lane >> 5;

    f32x2 sp[8];
    #pragma unroll
    for (int q = 0; q < 8; ++q) { sp[q].x = 0.0f; sp[q].y = 0.0f; }
    bf16x8 af;
    f32x16 nmv;

    for (int h = 0; h < 2; ++h) {
        if (h) {
            __syncthreads();
            if (doCol) {   // flush half-0 col partials, re-zero CS
                for (int c0 = threadIdx.x; c0 < HALF_COLS; c0 += THREADS) {
                    atomicAdd(&rCur[gb + c0], CS[c0]);
                    CS[c0] = 0.0f;
                }
            }
        }

        // staging: fast path only (never first)
        for (int jj = threadIdx.x; jj < HALF_COLS; jj += THREADS) {
            const int j = h * HALF_COLS + jj;
            uint4 f0  = CF0[cbase + j];
            uint2 f1l = CF1[cbase + j];
            float ysq = __uint_as_float(f1l.y);
            float hpj;
            if (doCol) {
                hpj = gPrev[gb + j];
                if (rPrev) hpj -= prevHalfK2 * __log2f(rPrev[gb + j]);
                if (writer) gDst[gb + j] = hpj;   // persist finalized g_{k-1}
            } else {
                hpj = hP[j];
            }
            float hhe = sigma * (hpj - ysq);
            unsigned short hA = f2bf(hhe); float r1 = hhe - bf2f(hA);
            unsigned short hB = f2bf(r1);  float r2 = r1 - bf2f(hB);
            unsigned short hC = f2bf(r2);
            uint4 f1 = make_uint4(f1l.x, f1l.x,
                                  (unsigned)hA | ((unsigned)hB << 16),
                                  (unsigned)hC);
            BF[jj >> 5][jj & 31]        = f0;
            BF[jj >> 5][32 + (jj & 31)] = f1;
        }
        __syncthreads();

        if (h == 0) {
            af = *(const bf16x8*)&AF[g][lane];
            #pragma unroll
            for (int r = 0; r < 16; ++r) {
                const int row = (r & 3) + 8 * (r >> 2) + 4 * khalf;
                nmv[r] = NM[g * 32 + row];
            }
        }

        const int tbase = c * (TILES_H / 2);
        #pragma unroll 2
        for (int t = 0; t < TILES_H / 2; ++t) {
            bf16x8 bf = *(const bf16x8*)&BF[tbase + t][lane];
            f32x16 acc = __builtin_amdgcn_mfma_f32_32x32x16_bf16(af, bf, nmv, 0, 0, 0);
            f32x2 ct; ct.x = 0.0f; ct.y = 0.0f;
            #pragma unroll
            for (int q = 0; q < 8; ++q) {
                f32x2 e;
                e.x = __builtin_amdgcn_exp2f(acc[2 * q]);
                e.y = __builtin_amdgcn_exp2f(acc[2 * q + 1]);
                asm("v_pk_add_f32 %0, %0, %1" : "+v"(sp[q]) : "v"(e));
                if (doCol)
                    asm("v_pk_add_f32 %0, %0, %1" : "+v"(ct) : "v"(e));
            }
            if (doCol) {   // per-tile column partial -> LDS accumulator
                float cv = ct.x + ct.y;
                cv += __shfl_xor(cv, 32, 64);
                if (lane < 32) atomicAdd(&CS[(tbase + t) * 32 + lane], cv);
            }
        }
    }

    __syncthreads();
    if (doCol) {   // flush half-1 col partials
        for (int c0 = threadIdx.x; c0 < HALF_COLS; c0 += THREADS)
            atomicAdd(&rCur[gb + HALF_COLS + c0], CS[c0]);
    }
    // ---- row-sum spill into dead BF space ----
    {
        f32x2* SP = (f32x2*)&BF[0][0];
        #pragma unroll
        for (int q = 0; q < 8; ++q)
            SP[(q * 4 + wave) * 64 + (lane ^ ((q & 3) << 3))] = sp[q];
    }
    __syncthreads();

    // ---- gather epilogue: 4 threads/row (r18-verified mapping) ----
    {
        const float* SPf = (const float*)&BF[0][0];
        const int v  = threadIdx.x >> 2;        // row 0..63
        const int p  = threadIdx.x & 3;
        const int gg = v >> 5, vv = v & 31;
        const int kh = (vv >> 2) & 1;
        const int r  = (vv & 3) | ((vv >> 3) << 2);
        const int q  = r >> 1, comp = r & 1;
        const int sw = (q & 3) << 3;
        float val = 0.0f;
        #pragma unroll
        for (int cc = 0; cc < 2; ++cc) {
            const int w = gg * 2 + cc;
            #pragma unroll
            for (int jj = 0; jj < 8; ++jj) {
                const int j = p * 8 + ((jj + v) & 7);
                const int l = kh * 32 + j;
                val += SPf[(((q * 4 + w) * 64) + (l ^ sw)) * 2 + comp];
            }
        }
        val += __shfl_xor(val, 1, 64);
        val += __shfl_xor(val, 2, 64);
        if (p == 0) {
            const int i = blockIdx.x * MROWS + v;
            float oldv = oldP[i];
            float res  = oldv - k2 * __log2f(val);
            outP[i] = 0.5f * (oldv + res);      // damped (interior launches)
        }
    }
}

extern "C" void kernel_launch(void* const* d_in, const int* in_sizes, int n_in,
                              void* d_out, int out_size, void* d_ws, size_t ws_size,
                              hipStream_t stream)
{
    const float* x = (const float*)d_in[0];
    const float* y = (const float*)d_in[1];
    float* out = (float*)d_out;

    // ws layout: P0, P1 (4 x B x NPTS), CF0 (2 x B x NPTS uint4),
    // CF1 (uint2, .y=ysq), G[2] (B x NPTS each), R[3] (B x NPTS each).
    const size_t potElems = (size_t)4 * BATCH * NPTS;
    const size_t colElems = (size_t)2 * BATCH * NPTS;
    const size_t bn       = (size_t)BATCH * NPTS;
    float* P0  = (float*)d_ws;
    float* P1  = P0 + potElems;
    uint4* CF0 = (uint4*)(P1 + potElems);
    uint2* CF1 = (uint2*)(CF0 + colElems);
    float* Gb  = (float*)(CF1 + colElems);
    float* Rb  = Gb + 2 * bn;
    float* G[2] = { Gb, Gb + bn };
    float* R[3] = { Rb, Rb + bn, Rb + 2 * bn };

    hipMemsetAsync(out, 0, BATCH * sizeof(float), stream);

    // Epsilon schedule
    double epsl[16];
    int ne = 0;
    epsl[ne++] = 4.0;
    const double stop = 2.0 * log(0.05);
    const double step = 2.0 * log(0.5);
    for (double e = 2.0 * log(2.0); e > stop; e += step)
        epsl[ne++] = exp(e);                // 4,1,0.25,0.0625,0.015625,0.00390625
    epsl[ne++] = 0.05 * 0.05;               // 0.0025  -> ne = 8

    float* src = P0;
    float* dst = P1;
    dim3 gridC(NPTS / CROWS, BATCH, 4);     // classic: 16 x 8 x 4
    dim3 gridM(NPTS / MROWS, BATCH, 3);     // merged:  32 x 8 x 3

    auto sig = [](double eps) { return (float)(M_LOG2E / eps); };
    auto kk2 = [](double eps) { return (float)(eps * M_LN2); };
    auto ik2 = [](double eps) { return (float)(1.0 / (eps * M_LN2)); };
    auto rc0 = [](double eps) { return (float)(eps * LOG_M); };

    // L0: classic init (writes invariants, seeds G[0]=g_0, zeroes R[1])
    softmin_classic<<<gridC, THREADS, 0, stream>>>(
        x, y, src, dst, CF0, CF1,
        nullptr, nullptr, G[0], R[1],
        sig(epsl[0]), kk2(epsl[0]), ik2(epsl[0]), rc0(epsl[0]), 0.0f,
        0, 1, 0, out);
    { float* t = src; src = dst; dst = t; }
    double prevEps = epsl[0];

    // L1..L8: merged damped loop. Launch k reads g_{k-2} from G[(k-1)&1] and
    // R_{k-1} to form g_{k-1} on the fly; writer persists it to G[k&1];
    // accumulates R_k into R[k%3]; zeroes R[(k+1)%3] for the next launch.
    for (int k = 1; k <= ne; ++k) {
        double eps = epsl[k - 1];
        softmin_merged<<<gridM, THREADS, 0, stream>>>(
            x, y, src, dst, CF0, CF1,
            G[(k - 1) & 1], (k >= 2) ? R[(k - 1) % 3] : nullptr, G[k & 1],
            R[k % 3], R[(k + 1) % 3],
            sig(eps), kk2(eps), ik2(eps), rc0(eps),
            (float)(0.5 * prevEps * M_LN2));
        { float* t = src; src = dst; dst = t; }
        prevEps = eps;
    }

    // L9: classic final extrapolation + output. Reads g_8 on the fly from
    // G[ne&1] (= g_7, stored by L8) and R[ne%3] (= R_8).
    softmin_classic<<<gridC, THREADS, 0, stream>>>(
        x, y, src, dst, CF0, CF1,
        G[ne & 1], R[ne % 3], nullptr, nullptr,
        sig(epsl[ne - 1]), kk2(epsl[ne - 1]), ik2(epsl[ne - 1]), rc0(epsl[ne - 1]),
        (float)(0.5 * prevEps * M_LN2),
        0, 0, 1, out);
}

// Round 4
// 239.933 us; speedup vs baseline: 1.0073x; 1.0073x over previous
//
#include <hip/hip_runtime.h>
#include <math.h>

// Problem constants (B=8 batches, N=M=2048 points, D=3)
#define BATCH 8
#define NPTS 2048
#define THREADS 256
#define HALF_COLS 1024         // columns staged per LDS stage
#define TILES_H 32             // 32-col MFMA tiles per staged half
#define CROWS 128              // classic kernel: 4 row-groups of 32
#define MROWS 64               // merged kernel: 2 row-groups x 2 col-splits
#define LOG_M 7.62559580411076 // ln(2048)

typedef __attribute__((ext_vector_type(8)))  __bf16 bf16x8;
typedef __attribute__((ext_vector_type(16))) float  f32x16;
typedef __attribute__((ext_vector_type(2)))  float  f32x2;

union FragU { unsigned short u[8]; uint4 v; };

__device__ __forceinline__ unsigned short f2bf(float f) {
    union { float f; unsigned u; } x; x.f = f;
    unsigned r = x.u + 0x7FFFu + ((x.u >> 16) & 1u);   // RNE
    return (unsigned short)(r >> 16);
}
__device__ __forceinline__ float bf2f(unsigned short b) {
    union { unsigned u; float f; } x; x.u = ((unsigned)b) << 16;
    return x.f;
}

// Single-pass softmin via 32x32x16 MFMA with estimated LSE shift (no max pass).
//   E_ij = 2^( sigma*(x.y + pot_j - ysq_j) + (old_i - rowconst_i)/k2 )
//        = exp((f_i + g_j - C_ij)/eps) / M            (exact identity)
// Row sums give ft_i = old_i - k2*log2(rowsum).  Col sums of the SAME E give
// the transposed update exactly: gt_j = g_j - k2*log2(colsum_j), so the g_ab
// plane is deleted on interior launches; readers of g in the NEXT launch
// finalize g = g_old - 0.5*k2_prev*log2(R) on the fly (writer block persists
// it into a ping-pong G buffer). Identity verified end-to-end in r20
// (absmax 0.0 through the full 8-launch chain).
// Falsification record:
//  r7  launch_bounds(512,4) pipeline: scratch spill
//  r10 poly-exp2 on VALU: v_exp_f32 blocks SIMD issue ~16cyc; no better
//  r11/r12 single-kernel fusion: grid-barrier cost >> 3us launch gaps
//  r13 triangle/mirror transpose: mirror scatter + imbalance ate the win
//  r15 32-row blocks at 2/CU: staging doubles, barriers 4x
//  r17 manual MFMA->exp2 pipeline: defeats compiler scheduling
//  r18 (WIN -5.6us): v_pk_add_f32 + transposed-LDS-spill reduction
//  r19 (WIN -24.7us): 128-row blocks halve staging+ramp; ysq in CF1.y
//  r20 (LOSS +10.3us): colsum identity correct, but 768 blocks at 2/CU =
//      512 resident + 256 backfill at 1 block/CU; tail + double CS flush ate
//      the 25% exp win. Geometry, not math.
// r21 (this round): same math as r20, fixed schedule: merged kernel at
// 3 blocks/CU (launch_bounds(256,3)) -> 768 blocks = 256 CU x 3 exactly,
// zero tail, per-SIMD work uniformly 75% of classic. CS widened to full
// 2048 cols (8 KB), zeroed once, flushed once (deletes mid-loop flush).
// LDS 42.3 KB x 3 = 127 KB < 160. VGPR must stay <=168 for 3/CU.
// A/B layout: m(n)=lane&31, k=(lane>>5)*8+j.
// C/D layout (verified m74/m101): col=lane&31, row=(reg&3)+8*(reg>>2)+4*(lane>>5).

// ---------------- classic 4-plane kernel (launches 0 and 9) ----------------
__global__ __launch_bounds__(THREADS, 2) void softmin_classic(
    const float* __restrict__ x, const float* __restrict__ y,
    const float* __restrict__ potSrc, float* __restrict__ potDst,
    uint4* __restrict__ CF0, uint2* __restrict__ CF1,
    const float* __restrict__ gPrev, const float* __restrict__ rPrev,
    float* __restrict__ gDst, float* __restrict__ zeroR,
    float sigma, float k2, float inv_k2, float rowc0, float prevHalfK2,
    int avg, int first, int last, float* __restrict__ out)
{
    __shared__ uint4 BF[TILES_H][64];     // 32 KB: B frags (one half), slot=lane
    __shared__ uint4 AF[4][64];           //  4 KB: A frags (4 row-groups)
    __shared__ float NM[CROWS];           // -m2_hat per row; res stash on last

    const int type  = blockIdx.z;
    const int batch = blockIdx.y;

    if (zeroR) {   // L0: zero the R buffer launch 1 will accumulate into
        const int lid = ((blockIdx.z * gridDim.y + blockIdx.y) * gridDim.x + blockIdx.x);
        if (threadIdx.x < 32) zeroR[lid * 32 + threadIdx.x] = 0.0f;
    }

    const float* rowP;
    const float* colP;
    int hslot, oslot, cs;
    if (type == 0)      { rowP = x; colP = y; hslot = 1; oslot = 0; cs = 1; }  // f_ba
    else if (type == 1) { rowP = y; colP = x; hslot = 0; oslot = 1; cs = 0; }  // g_ab
    else if (type == 2) { rowP = x; colP = x; hslot = 2; oslot = 2; cs = 0; }  // f_aa
    else                { rowP = y; colP = y; hslot = 3; oslot = 3; cs = 1; }  // g_bb

    rowP += batch * NPTS * 3;
    colP += batch * NPTS * 3;
    const float* hP   = potSrc + (hslot * BATCH + batch) * NPTS;
    const float* oldP = potSrc + (oslot * BATCH + batch) * NPTS;
    float*       outP = potDst + (oslot * BATCH + batch) * NPTS;
    const size_t cbase = ((size_t)cs * BATCH + batch) * NPTS;

    // L9: potSrc slot 1 (g_ab) is stale; finalize from G chain + raw colsums.
    const bool  fixH = (rPrev != nullptr) && (hslot == 1);
    const bool  fixO = (rPrev != nullptr) && (oslot == 1);
    const float* gB  = gPrev + batch * NPTS;
    const float* rB  = rPrev + batch * NPTS;
    float* gW = (gDst != nullptr && oslot == 1) ? (gDst + batch * NPTS) : nullptr;

    // ---- stage A fragments: 4 groups x 64 slots = all 256 threads ----
    {
        const int gg = threadIdx.x >> 6, idx = threadIdx.x & 63;
        const int row = blockIdx.x * CROWS + gg * 32 + (idx & 31);
        float x0 = rowP[3 * row + 0], x1 = rowP[3 * row + 1], x2 = rowP[3 * row + 2];
        float p0 = sigma * (x0 - 0.5f), p1 = sigma * (x1 - 0.5f), p2 = sigma * (x2 - 0.5f);
        unsigned short h0 = f2bf(p0); unsigned short l0 = f2bf(p0 - bf2f(h0));
        unsigned short h1 = f2bf(p1); unsigned short l1 = f2bf(p1 - bf2f(h1));
        unsigned short h2 = f2bf(p2); unsigned short l2 = f2bf(p2 - bf2f(h2));
        FragU f;
        if (idx < 32) {   // k0-7: dim0 (xh,xh,xl,xl), dim1 (xh,xh,xl,xl)
            f.u[0] = h0; f.u[1] = h0; f.u[2] = l0; f.u[3] = l0;
            f.u[4] = h1; f.u[5] = h1; f.u[6] = l1; f.u[7] = l1;
        } else {          // k8-15: dim2 (xh,xh,xl,xl), 1,1,1, 0
            f.u[0] = h2; f.u[1] = h2; f.u[2] = l2; f.u[3] = l2;
            f.u[4] = 0x3F80; f.u[5] = 0x3F80; f.u[6] = 0x3F80; f.u[7] = 0;
        }
        AF[gg][idx] = f.v;
    }
    if (threadIdx.x < CROWS) {
        const int r = threadIdx.x;
        const int i = blockIdx.x * CROWS + r;
        float x0 = rowP[3 * i + 0], x1 = rowP[3 * i + 1], x2 = rowP[3 * i + 2];
        float p0 = x0 - 0.5f, p1 = x1 - 0.5f, p2 = x2 - 0.5f;
        float rowconst = 0.5f * (p0 * p0 + p1 * p1 + p2 * p2) + rowc0;
        float oldv = first ? 0.0f
                   : (fixO ? (gB[i] - prevHalfK2 * __log2f(rB[i])) : oldP[i]);
        NM[r] = (oldv - rowconst) * inv_k2;
    }

    const int lane = threadIdx.x & 63;
    const int g    = threadIdx.x >> 6;   // wave index == row-group 0..3
    const int khalf = lane >> 5;

    f32x2 sp[8];
    #pragma unroll
    for (int q = 0; q < 8; ++q) { sp[q].x = 0.0f; sp[q].y = 0.0f; }
    bf16x8 af;
    f32x16 nmv;

    for (int h = 0; h < 2; ++h) {
        if (h) __syncthreads();

        if (first) {
            const int writer = (blockIdx.x == 0) && (type <= 1);
            for (int jj = threadIdx.x; jj < HALF_COLS; jj += THREADS) {
                const int j = h * HALF_COLS + jj;
                float y0 = colP[3 * j + 0], y1 = colP[3 * j + 1], y2 = colP[3 * j + 2];
                float p0 = y0 - 0.5f, p1 = y1 - 0.5f, p2 = y2 - 0.5f;
                unsigned short h0 = f2bf(p0); unsigned short l0 = f2bf(p0 - bf2f(h0));
                unsigned short h1 = f2bf(p1); unsigned short l1 = f2bf(p1 - bf2f(h1));
                unsigned short h2 = f2bf(p2); unsigned short l2 = f2bf(p2 - bf2f(h2));
                float ysq = 0.5f * (p0 * p0 + p1 * p1 + p2 * p2);
                float hhe = -sigma * ysq;                    // pot == 0
                unsigned short hA = f2bf(hhe); float r1 = hhe - bf2f(hA);
                unsigned short hB = f2bf(r1);  float r2 = r1 - bf2f(hB);
                unsigned short hC = f2bf(r2);
                FragU f0, f1;
                f0.u[0] = h0; f0.u[1] = l0; f0.u[2] = h0; f0.u[3] = l0;
                f0.u[4] = h1; f0.u[5] = l1; f0.u[6] = h1; f0.u[7] = l1;
                f1.u[0] = h2; f1.u[1] = l2; f1.u[2] = h2; f1.u[3] = l2;
                f1.u[4] = hA; f1.u[5] = hB; f1.u[6] = hC; f1.u[7] = 0;
                BF[jj >> 5][jj & 31]        = f0.v;
                BF[jj >> 5][32 + (jj & 31)] = f1.v;
                if (writer) {
                    CF0[cbase + j] = f0.v;
                    CF1[cbase + j] = make_uint2(f1.v.x, __float_as_uint(ysq));
                }
            }
        } else {
            for (int jj = threadIdx.x; jj < HALF_COLS; jj += THREADS) {
                const int j = h * HALF_COLS + jj;
                uint4 f0  = CF0[cbase + j];
                uint2 f1l = CF1[cbase + j];
                float ysq = __uint_as_float(f1l.y);
                float hpj = fixH ? (gB[j] - prevHalfK2 * __log2f(rB[j])) : hP[j];
                float hhe = sigma * (hpj - ysq);
                unsigned short hA = f2bf(hhe); float r1 = hhe - bf2f(hA);
                unsigned short hB = f2bf(r1);  float r2 = r1 - bf2f(hB);
                unsigned short hC = f2bf(r2);
                uint4 f1 = make_uint4(f1l.x, f1l.x,
                                      (unsigned)hA | ((unsigned)hB << 16),
                                      (unsigned)hC);
                BF[jj >> 5][jj & 31]        = f0;
                BF[jj >> 5][32 + (jj & 31)] = f1;
            }
        }
        __syncthreads();

        if (h == 0) {
            af = *(const bf16x8*)&AF[g][lane];
            #pragma unroll
            for (int r = 0; r < 16; ++r) {
                const int row = (r & 3) + 8 * (r >> 2) + 4 * khalf;
                nmv[r] = NM[g * 32 + row];
            }
        }

        #pragma unroll 2
        for (int t = 0; t < TILES_H; ++t) {
            bf16x8 bf = *(const bf16x8*)&BF[t][lane];
            f32x16 acc = __builtin_amdgcn_mfma_f32_32x32x16_bf16(af, bf, nmv, 0, 0, 0);
            #pragma unroll
            for (int q = 0; q < 8; ++q) {
                f32x2 e;
                e.x = __builtin_amdgcn_exp2f(acc[2 * q]);
                e.y = __builtin_amdgcn_exp2f(acc[2 * q + 1]);
                asm("v_pk_add_f32 %0, %0, %1" : "+v"(sp[q]) : "v"(e));
            }
        }
    }

    // ---- transposed reduction via spill into dead BF space ----
    __syncthreads();
    {
        f32x2* SP = (f32x2*)&BF[0][0];
        #pragma unroll
        for (int q = 0; q < 8; ++q)
            SP[(q * 4 + g) * 64 + (lane ^ ((q & 3) << 3))] = sp[q];
    }
    __syncthreads();

    {
        const float* SPf = (const float*)&BF[0][0];
        const int v  = threadIdx.x >> 1;        // row 0..127
        const int p  = threadIdx.x & 1;
        const int gg = v >> 5, vv = v & 31;
        const int kh = (vv >> 2) & 1;
        const int r  = (vv & 3) | ((vv >> 3) << 2);
        const int q  = r >> 1, comp = r & 1;
        const int sw = (q & 3) << 3;
        float val = 0.0f;
        #pragma unroll
        for (int jj = 0; jj < 16; ++jj) {
            const int j = (p * 16 + jj + v) & 31;
            const int l = kh * 32 + j;
            val += SPf[(((q * 4 + gg) * 64) + (l ^ sw)) * 2 + comp];
        }
        val += __shfl_xor(val, 1, 64);
        if (p == 0) {
            const int i = blockIdx.x * CROWS + v;
            float oldv = first ? 0.0f
                       : (fixO ? (gB[i] - prevHalfK2 * __log2f(rB[i])) : oldP[i]);
            float res  = oldv - k2 * __log2f(val);
            outP[i] = avg ? 0.5f * (oldv + res) : res;
            if (gW) gW[i] = res;     // L0: seed G0 with g_0
            if (last) NM[v] = res;
        }
    }

    if (last) {
        __syncthreads();
        if (g == 0) {
            float v2 = NM[lane] + NM[64 + lane];
            #pragma unroll
            for (int off = 32; off >= 1; off >>= 1)
                v2 += __shfl_xor(v2, off, 64);
            if (lane == 0) {
                float sign = (type >= 2) ? -1.0f : 1.0f;
                atomicAdd(out + batch, sign * v2 * (1.0f / NPTS));
            }
        }
    }
}

// -------- merged 3-plane kernel (launches 1..8): z=0 xy(+colsum), 1 xx, 2 yy
// 3 blocks/CU: 768 blocks = 256 CU x 3, single resident generation, no tail.
__global__ __launch_bounds__(THREADS, 3) void softmin_merged(
    const float* __restrict__ x, const float* __restrict__ y,
    const float* __restrict__ potSrc, float* __restrict__ potDst,
    const uint4* __restrict__ CF0, const uint2* __restrict__ CF1,
    const float* __restrict__ gPrev, const float* __restrict__ rPrev,
    float* __restrict__ gDst, float* __restrict__ rCur, float* __restrict__ rZero,
    float sigma, float k2, float inv_k2, float rowc0, float prevHalfK2)
{
    __shared__ uint4 BF[TILES_H][64];     // 32 KB
    __shared__ uint4 AF[2][64];           //  2 KB
    __shared__ float NM[MROWS];
    __shared__ float CS[NPTS];            //  8 KB col partials, full width

    const int type  = blockIdx.z;
    const int batch = blockIdx.y;
    const int doCol = (type == 0);

    const float* rowP; const float* colP;
    int oslot, hslot, cs;
    if (type == 0)      { rowP = x; colP = y; oslot = 0; hslot = 0; cs = 1; }  // xy merged
    else if (type == 1) { rowP = x; colP = x; oslot = 2; hslot = 2; cs = 0; }  // f_aa
    else                { rowP = y; colP = y; oslot = 3; hslot = 3; cs = 1; }  // g_bb

    rowP += batch * NPTS * 3;
    colP += batch * NPTS * 3;
    const float* hP   = potSrc + (hslot * BATCH + batch) * NPTS;  // unused z=0
    const float* oldP = potSrc + (oslot * BATCH + batch) * NPTS;
    float*       outP = potDst + (oslot * BATCH + batch) * NPTS;
    const size_t cbase = ((size_t)cs * BATCH + batch) * NPTS;
    const int gb = batch * NPTS;
    const int writer = doCol && (blockIdx.x == 0);

    if (doCol) {
        for (int c0 = threadIdx.x; c0 < NPTS; c0 += THREADS) CS[c0] = 0.0f;
        const int zb = (batch * 32 + blockIdx.x) * 64;   // zero next launch's R
        if (threadIdx.x < 64) rZero[zb + threadIdx.x] = 0.0f;
    }

    // ---- A fragments (2 groups) + NM ----
    if (threadIdx.x < 128) {
        const int gg = threadIdx.x >> 6, idx = threadIdx.x & 63;
        const int row = blockIdx.x * MROWS + gg * 32 + (idx & 31);
        float x0 = rowP[3 * row + 0], x1 = rowP[3 * row + 1], x2 = rowP[3 * row + 2];
        float p0 = sigma * (x0 - 0.5f), p1 = sigma * (x1 - 0.5f), p2 = sigma * (x2 - 0.5f);
        unsigned short h0 = f2bf(p0); unsigned short l0 = f2bf(p0 - bf2f(h0));
        unsigned short h1 = f2bf(p1); unsigned short l1 = f2bf(p1 - bf2f(h1));
        unsigned short h2 = f2bf(p2); unsigned short l2 = f2bf(p2 - bf2f(h2));
        FragU f;
        if (idx < 32) {
            f.u[0] = h0; f.u[1] = h0; f.u[2] = l0; f.u[3] = l0;
            f.u[4] = h1; f.u[5] = h1; f.u[6] = l1; f.u[7] = l1;
        } else {
            f.u[0] = h2; f.u[1] = h2; f.u[2] = l2; f.u[3] = l2;
            f.u[4] = 0x3F80; f.u[5] = 0x3F80; f.u[6] = 0x3F80; f.u[7] = 0;
        }
        AF[gg][idx] = f.v;
    } else if (threadIdx.x < 128 + MROWS) {
        const int r = threadIdx.x - 128;
        const int i = blockIdx.x * MROWS + r;
        float x0 = rowP[3 * i + 0], x1 = rowP[3 * i + 1], x2 = rowP[3 * i + 2];
        float p0 = x0 - 0.5f, p1 = x1 - 0.5f, p2 = x2 - 0.5f;
        float rowconst = 0.5f * (p0 * p0 + p1 * p1 + p2 * p2) + rowc0;
        NM[r] = (oldP[i] - rowconst) * inv_k2;
    }

    const int lane = threadIdx.x & 63;
    const int wave = threadIdx.x >> 6;
    const int g    = wave >> 1;        // row-group 0..1
    const int c    = wave & 1;         // col-split 0..1
    const int khalf = lane >> 5;

    f32x2 sp[8];
    #pragma unroll
    for (int q = 0; q < 8; ++q) { sp[q].x = 0.0f; sp[q].y = 0.0f; }
    bf16x8 af;
    f32x16 nmv;

    for (int h = 0; h < 2; ++h) {
        if (h) __syncthreads();

        // staging: fast path only (never first)
        for (int jj = threadIdx.x; jj < HALF_COLS; jj += THREADS) {
            const int j = h * HALF_COLS + jj;
            uint4 f0  = CF0[cbase + j];
            uint2 f1l = CF1[cbase + j];
            float ysq = __uint_as_float(f1l.y);
            float hpj;
            if (doCol) {
                hpj = gPrev[gb + j];
                if (rPrev) hpj -= prevHalfK2 * __log2f(rPrev[gb + j]);
                if (writer) gDst[gb + j] = hpj;   // persist finalized g_{k-1}
            } else {
                hpj = hP[j];
            }
            float hhe = sigma * (hpj - ysq);
            unsigned short hA = f2bf(hhe); float r1 = hhe - bf2f(hA);
            unsigned short hB = f2bf(r1);  float r2 = r1 - bf2f(hB);
            unsigned short hC = f2bf(r2);
            uint4 f1 = make_uint4(f1l.x, f1l.x,
                                  (unsigned)hA | ((unsigned)hB << 16),
                                  (unsigned)hC);
            BF[jj >> 5][jj & 31]        = f0;
            BF[jj >> 5][32 + (jj & 31)] = f1;
        }
        __syncthreads();

        if (h == 0) {
            af = *(const bf16x8*)&AF[g][lane];
            #pragma unroll
            for (int r = 0; r < 16; ++r) {
                const int row = (r & 3) + 8 * (r >> 2) + 4 * khalf;
                nmv[r] = NM[g * 32 + row];
            }
        }

        const int tbase = c * (TILES_H / 2);
        #pragma unroll 2
        for (int t = 0; t < TILES_H / 2; ++t) {
            bf16x8 bf = *(const bf16x8*)&BF[tbase + t][lane];
            f32x16 acc = __builtin_amdgcn_mfma_f32_32x32x16_bf16(af, bf, nmv, 0, 0, 0);
            f32x2 ct; ct.x = 0.0f; ct.y = 0.0f;
            #pragma unroll
            for (int q = 0; q < 8; ++q) {
                f32x2 e;
                e.x = __builtin_amdgcn_exp2f(acc[2 * q]);
                e.y = __builtin_amdgcn_exp2f(acc[2 * q + 1]);
                asm("v_pk_add_f32 %0, %0, %1" : "+v"(sp[q]) : "v"(e));
                if (doCol)
                    asm("v_pk_add_f32 %0, %0, %1" : "+v"(ct) : "v"(e));
            }
            if (doCol) {   // per-tile column partial -> full-width LDS accum
                float cv = ct.x + ct.y;
                cv += __shfl_xor(cv, 32, 64);
                if (lane < 32)
                    atomicAdd(&CS[h * HALF_COLS + (tbase + t) * 32 + lane], cv);
            }
        }
    }

    __syncthreads();
    if (doCol) {   // single flush of all 2048 col partials
        for (int c0 = threadIdx.x; c0 < NPTS; c0 += THREADS)
            atomicAdd(&rCur[gb + c0], CS[c0]);
    }
    // ---- row-sum spill into dead BF space ----
    {
        f32x2* SP = (f32x2*)&BF[0][0];
        #pragma unroll
        for (int q = 0; q < 8; ++q)
            SP[(q * 4 + wave) * 64 + (lane ^ ((q & 3) << 3))] = sp[q];
    }
    __syncthreads();

    // ---- gather epilogue: 4 threads/row (r18-verified mapping) ----
    {
        const float* SPf = (const float*)&BF[0][0];
        const int v  = threadIdx.x >> 2;        // row 0..63
        const int p  = threadIdx.x & 3;
        const int gg = v >> 5, vv = v & 31;
        const int kh = (vv >> 2) & 1;
        const int r  = (vv & 3) | ((vv >> 3) << 2);
        const int q  = r >> 1, comp = r & 1;
        const int sw = (q & 3) << 3;
        float val = 0.0f;
        #pragma unroll
        for (int cc = 0; cc < 2; ++cc) {
            const int w = gg * 2 + cc;
            #pragma unroll
            for (int jj = 0; jj < 8; ++jj) {
                const int j = p * 8 + ((jj + v) & 7);
                const int l = kh * 32 + j;
                val += SPf[(((q * 4 + w) * 64) + (l ^ sw)) * 2 + comp];
            }
        }
        val += __shfl_xor(val, 1, 64);
        val += __shfl_xor(val, 2, 64);
        if (p == 0) {
            const int i = blockIdx.x * MROWS + v;
            float oldv = oldP[i];
            float res  = oldv - k2 * __log2f(val);
            outP[i] = 0.5f * (oldv + res);      // damped (interior launches)
        }
    }
}

extern "C" void kernel_launch(void* const* d_in, const int* in_sizes, int n_in,
                              void* d_out, int out_size, void* d_ws, size_t ws_size,
                              hipStream_t stream)
{
    const float* x = (const float*)d_in[0];
    const float* y = (const float*)d_in[1];
    float* out = (float*)d_out;

    // ws layout: P0, P1 (4 x B x NPTS), CF0 (2 x B x NPTS uint4),
    // CF1 (uint2, .y=ysq), G[2] (B x NPTS each), R[3] (B x NPTS each).
    const size_t potElems = (size_t)4 * BATCH * NPTS;
    const size_t colElems = (size_t)2 * BATCH * NPTS;
    const size_t bn       = (size_t)BATCH * NPTS;
    float* P0  = (float*)d_ws;
    float* P1  = P0 + potElems;
    uint4* CF0 = (uint4*)(P1 + potElems);
    uint2* CF1 = (uint2*)(CF0 + colElems);
    float* Gb  = (float*)(CF1 + colElems);
    float* Rb  = Gb + 2 * bn;
    float* G[2] = { Gb, Gb + bn };
    float* R[3] = { Rb, Rb + bn, Rb + 2 * bn };

    hipMemsetAsync(out, 0, BATCH * sizeof(float), stream);

    // Epsilon schedule
    double epsl[16];
    int ne = 0;
    epsl[ne++] = 4.0;
    const double stop = 2.0 * log(0.05);
    const double step = 2.0 * log(0.5);
    for (double e = 2.0 * log(2.0); e > stop; e += step)
        epsl[ne++] = exp(e);                // 4,1,0.25,0.0625,0.015625,0.00390625
    epsl[ne++] = 0.05 * 0.05;               // 0.0025  -> ne = 8

    float* src = P0;
    float* dst = P1;
    dim3 gridC(NPTS / CROWS, BATCH, 4);     // classic: 16 x 8 x 4
    dim3 gridM(NPTS / MROWS, BATCH, 3);     // merged:  32 x 8 x 3 = 768 = 256CU x 3

    auto sig = [](double eps) { return (float)(M_LOG2E / eps); };
    auto kk2 = [](double eps) { return (float)(eps * M_LN2); };
    auto ik2 = [](double eps) { return (float)(1.0 / (eps * M_LN2)); };
    auto rc0 = [](double eps) { return (float)(eps * LOG_M); };

    // L0: classic init (writes invariants, seeds G[0]=g_0, zeroes R[1])
    softmin_classic<<<gridC, THREADS, 0, stream>>>(
        x, y, src, dst, CF0, CF1,
        nullptr, nullptr, G[0], R[1],
        sig(epsl[0]), kk2(epsl[0]), ik2(epsl[0]), rc0(epsl[0]), 0.0f,
        0, 1, 0, out);
    { float* t = src; src = dst; dst = t; }
    double prevEps = epsl[0];

    // L1..L8: merged damped loop. Launch k reads g_{k-2} from G[(k-1)&1] and
    // R_{k-1} to form g_{k-1} on the fly; writer persists it to G[k&1];
    // accumulates R_k into R[k%3]; zeroes R[(k+1)%3] for the next launch.
    for (int k = 1; k <= ne; ++k) {
        double eps = epsl[k - 1];
        softmin_merged<<<gridM, THREADS, 0, stream>>>(
            x, y, src, dst, CF0, CF1,
            G[(k - 1) & 1], (k >= 2) ? R[(k - 1) % 3] : nullptr, G[k & 1],
            R[k % 3], R[(k + 1) % 3],
            sig(eps), kk2(eps), ik2(eps), rc0(eps),
            (float)(0.5 * prevEps * M_LN2));
        { float* t = src; src = dst; dst = t; }
        prevEps = eps;
    }

    // L9: classic final extrapolation + output. Reads g_8 on the fly from
    // G[ne&1] (= g_7, stored by L8) and R[ne%3] (= R_8).
    softmin_classic<<<gridC, THREADS, 0, stream>>>(
        x, y, src, dst, CF0, CF1,
        G[ne & 1], R[ne % 3], nullptr, nullptr,
        sig(epsl[ne - 1]), kk2(epsl[ne - 1]), ik2(epsl[ne - 1]), rc0(epsl[ne - 1]),
        (float)(0.5 * prevEps * M_LN2),
        0, 0, 1, out);
}

// Round 5
// 234.706 us; speedup vs baseline: 1.0297x; 1.0223x over previous
//
#include <hip/hip_runtime.h>
#include <math.h>

// Problem constants (B=8 batches, N=M=2048 points, D=3)
#define BATCH 8
#define NPTS 2048
#define THREADS 256            // 4 waves = 4 row-groups of 32 rows
#define HALF_COLS 1024         // columns staged per LDS stage
#define TILES_H 32             // 32-col MFMA tiles per staged half
#define ROWS_PER_BLOCK 128     // 4 row-groups of 32
#define LOG_M 7.62559580411076 // ln(2048)

typedef __attribute__((ext_vector_type(8)))  __bf16 bf16x8;
typedef __attribute__((ext_vector_type(16))) float  f32x16;
typedef __attribute__((ext_vector_type(2)))  float  f32x2;

union FragU { unsigned short u[8]; uint4 v; };

__device__ __forceinline__ unsigned short f2bf(float f) {
    union { float f; unsigned u; } x; x.f = f;
    unsigned r = x.u + 0x7FFFu + ((x.u >> 16) & 1u);   // RNE
    return (unsigned short)(r >> 16);
}
__device__ __forceinline__ float bf2f(unsigned short b) {
    union { unsigned u; float f; } x; x.u = ((unsigned)b) << 16;
    return x.f;
}

// Single-pass softmin via 32x32x16 MFMA with estimated LSE shift (no max pass).
//   arg_ij = (x'_i . y'_j + pot_j - 0.5|y'_j|^2) * log2(e)/eps  (log2 domain)
// K=16 slots: per dim, (xh,xh,xl,xl)x(yh,yl,yh,yl) = 4 products (12 slots),
// 3-way split of sigma*hhe vs 1.0 (3 slots), slot 15 zero; sigma=log2e/eps.
// Shift m2_hat = (rowconst - old)/k2 enters as the MFMA C operand;
// res = old - k2*log2(s) (rowconst cancels).
// Falsification record (r7-r17 prior session, r18-r21 this session):
//  r7  launch_bounds(512,4) pipeline: scratch spill
//  r10 poly-exp2 on VALU: v_exp_f32 blocks SIMD issue ~16cyc; no better
//  r11/r12 single-kernel fusion: grid-barrier cost >> 3us launch gaps
//  r13 triangle/mirror transpose: mirror scatter + imbalance ate the win
//  r15 32-row blocks at 2/CU: staging doubles, barriers 4x
//  r17 manual MFMA->exp2 pipeline: defeats compiler scheduling
//  r18 (WIN -5.6us): v_pk_add_f32 + transposed-LDS-spill reduction
//  r19 (WIN -24.7us): 128-row blocks halve staging+ramp; ysq in CF1.y  [231.3]
//  r20/r21 (LOSS +10/+8.6 vs r19): colsum transpose identity is exact
//      (absmax 0.0 through the chain) but schedule-falsified at both 2/CU
//      (tail generation) and 3/CU (staging:compute ratio doubles at 64-row
//      blocks, 3rd barrier-phase set, VGPR cap 168 risk). ABANDONED.
// r22 (this round): r19 base + double-buffered B-staging. BF[2] (64 KB,
// 68.5 KB/block total, 2 blocks/CU = 137 < 160): stage h0, barrier,
// stage h1 into buf1 DURING h0 compute (no WAR barrier), barrier, compute
// h1. Removes the exposed global-load latency + ds_write serial segment of
// the second staging phase and one barrier; SP spill reuses buf0 without a
// pre-spill barrier (buf0 reads all completed before barrier 2).
// A/B layout: m(n)=lane&31, k=(lane>>5)*8+j.
// C/D layout (verified m74/m101): col=lane&31, row=(reg&3)+8*(reg>>2)+4*(lane>>5).
__global__ __launch_bounds__(THREADS, 2) void softmin_pass(
    const float* __restrict__ x, const float* __restrict__ y,
    const float* __restrict__ potSrc, float* __restrict__ potDst,
    uint4* __restrict__ CF0, uint2* __restrict__ CF1,
    float sigma, float k2, float inv_k2, float rowc0,
    int avg, int first, int last, float* __restrict__ out)
{
    __shared__ uint4 BF[2][TILES_H][64];  // 64 KB: B frags, double-buffered
    __shared__ uint4 AF[4][64];           //  4 KB: A frags (4 row-groups)
    __shared__ float NM[ROWS_PER_BLOCK];  // -m2_hat per row; res stash on last

    const int type  = blockIdx.z;
    const int batch = blockIdx.y;

    const float* rowP;
    const float* colP;
    int hslot, oslot, cs;
    if (type == 0)      { rowP = x; colP = y; hslot = 1; oslot = 0; cs = 1; }  // f_ba
    else if (type == 1) { rowP = y; colP = x; hslot = 0; oslot = 1; cs = 0; }  // g_ab
    else if (type == 2) { rowP = x; colP = x; hslot = 2; oslot = 2; cs = 0; }  // f_aa
    else                { rowP = y; colP = y; hslot = 3; oslot = 3; cs = 1; }  // g_bb

    rowP += batch * NPTS * 3;
    colP += batch * NPTS * 3;
    const float* hP   = potSrc + (hslot * BATCH + batch) * NPTS;
    const float* oldP = potSrc + (oslot * BATCH + batch) * NPTS;
    float*       outP = potDst + (oslot * BATCH + batch) * NPTS;
    const size_t cbase = ((size_t)cs * BATCH + batch) * NPTS;

    // ---- stage A fragments: 4 groups x 64 slots = all 256 threads ----
    {
        const int gg = threadIdx.x >> 6, idx = threadIdx.x & 63;
        const int row = blockIdx.x * ROWS_PER_BLOCK + gg * 32 + (idx & 31);
        float x0 = rowP[3 * row + 0], x1 = rowP[3 * row + 1], x2 = rowP[3 * row + 2];
        float p0 = sigma * (x0 - 0.5f), p1 = sigma * (x1 - 0.5f), p2 = sigma * (x2 - 0.5f);
        unsigned short h0 = f2bf(p0); unsigned short l0 = f2bf(p0 - bf2f(h0));
        unsigned short h1 = f2bf(p1); unsigned short l1 = f2bf(p1 - bf2f(h1));
        unsigned short h2 = f2bf(p2); unsigned short l2 = f2bf(p2 - bf2f(h2));
        FragU f;
        if (idx < 32) {   // k0-7: dim0 (xh,xh,xl,xl), dim1 (xh,xh,xl,xl)
            f.u[0] = h0; f.u[1] = h0; f.u[2] = l0; f.u[3] = l0;
            f.u[4] = h1; f.u[5] = h1; f.u[6] = l1; f.u[7] = l1;
        } else {          // k8-15: dim2 (xh,xh,xl,xl), 1,1,1, 0
            f.u[0] = h2; f.u[1] = h2; f.u[2] = l2; f.u[3] = l2;
            f.u[4] = 0x3F80; f.u[5] = 0x3F80; f.u[6] = 0x3F80; f.u[7] = 0;
        }
        AF[gg][idx] = f.v;
    }
    if (threadIdx.x < ROWS_PER_BLOCK) {
        // ---- per-row shift: NM[r] = (old - rowconst)/k2 = -m2_hat ----
        const int r = threadIdx.x;
        const int i = blockIdx.x * ROWS_PER_BLOCK + r;
        float x0 = rowP[3 * i + 0], x1 = rowP[3 * i + 1], x2 = rowP[3 * i + 2];
        float p0 = x0 - 0.5f, p1 = x1 - 0.5f, p2 = x2 - 0.5f;
        float rowconst = 0.5f * (p0 * p0 + p1 * p1 + p2 * p2) + rowc0;
        float oldv = first ? 0.0f : oldP[i];
        NM[r] = (oldv - rowconst) * inv_k2;
    }

    const int lane = threadIdx.x & 63;
    const int g    = threadIdx.x >> 6;   // wave index == row-group 0..3
    const int khalf = lane >> 5;

    // accumulator as 8 packed pairs: sp[q] = {s[2q], s[2q+1]}
    f32x2 sp[8];
    #pragma unroll
    for (int q = 0; q < 8; ++q) { sp[q].x = 0.0f; sp[q].y = 0.0f; }
    bf16x8 af;
    f32x16 nmv;

    // ---- staging helper: fill BF[h] with columns [h*1024, h*1024+1024) ----
    auto stage_half = [&](int h) {
        if (first) {
            // slow path: full recompute from coords (pot == 0); the writer
            // block of each (colset,batch) also stores the invariants.
            const int writer = (blockIdx.x == 0) && (type <= 1);
            for (int jj = threadIdx.x; jj < HALF_COLS; jj += THREADS) {
                const int j = h * HALF_COLS + jj;
                float y0 = colP[3 * j + 0], y1 = colP[3 * j + 1], y2 = colP[3 * j + 2];
                float p0 = y0 - 0.5f, p1 = y1 - 0.5f, p2 = y2 - 0.5f;
                unsigned short h0 = f2bf(p0); unsigned short l0 = f2bf(p0 - bf2f(h0));
                unsigned short h1 = f2bf(p1); unsigned short l1 = f2bf(p1 - bf2f(h1));
                unsigned short h2 = f2bf(p2); unsigned short l2 = f2bf(p2 - bf2f(h2));
                float ysq = 0.5f * (p0 * p0 + p1 * p1 + p2 * p2);
                float hhe = -sigma * ysq;                    // pot == 0
                unsigned short hA = f2bf(hhe); float r1 = hhe - bf2f(hA);
                unsigned short hB = f2bf(r1);  float r2 = r1 - bf2f(hB);
                unsigned short hC = f2bf(r2);
                FragU f0, f1;
                // k0-7: dim0 (yh,yl,yh,yl), dim1 (yh,yl,yh,yl)
                f0.u[0] = h0; f0.u[1] = l0; f0.u[2] = h0; f0.u[3] = l0;
                f0.u[4] = h1; f0.u[5] = l1; f0.u[6] = h1; f0.u[7] = l1;
                // k8-15: dim2 (yh,yl,yh,yl), hA,hB,hC, 0
                f1.u[0] = h2; f1.u[1] = l2; f1.u[2] = h2; f1.u[3] = l2;
                f1.u[4] = hA; f1.u[5] = hB; f1.u[6] = hC; f1.u[7] = 0;
                BF[h][jj >> 5][jj & 31]        = f0.v;   // k0-7  (lanes 0-31)
                BF[h][jj >> 5][32 + (jj & 31)] = f1.v;   // k8-15 (lanes 32-63)
                if (writer) {
                    CF0[cbase + j] = f0.v;
                    // CF1.x = (h2,l2); CF1.y stores ysq
                    CF1[cbase + j] = make_uint2(f1.v.x, __float_as_uint(ysq));
                }
            }
        } else {
            // fast path: invariants from global (L2-hit), only hhe recomputed
            for (int jj = threadIdx.x; jj < HALF_COLS; jj += THREADS) {
                const int j = h * HALF_COLS + jj;
                uint4 f0  = CF0[cbase + j];
                uint2 f1l = CF1[cbase + j];
                float ysq = __uint_as_float(f1l.y);
                float hhe = sigma * (hP[j] - ysq);
                unsigned short hA = f2bf(hhe); float r1 = hhe - bf2f(hA);
                unsigned short hB = f2bf(r1);  float r2 = r1 - bf2f(hB);
                unsigned short hC = f2bf(r2);
                uint4 f1 = make_uint4(f1l.x, f1l.x,
                                      (unsigned)hA | ((unsigned)hB << 16),
                                      (unsigned)hC);
                BF[h][jj >> 5][jj & 31]        = f0;     // k0-7  (lanes 0-31)
                BF[h][jj >> 5][32 + (jj & 31)] = f1;     // k8-15 (lanes 32-63)
            }
        }
    };

    // ---- compute helper: 32 tiles from BF[h], accumulate exp2 into sp ----
    auto compute_half = [&](int h) {
        #pragma unroll 2
        for (int t = 0; t < TILES_H; ++t) {
            bf16x8 bf = *(const bf16x8*)&BF[h][t][lane];
            f32x16 acc = __builtin_amdgcn_mfma_f32_32x32x16_bf16(af, bf, nmv, 0, 0, 0);
            #pragma unroll
            for (int q = 0; q < 8; ++q) {
                f32x2 e;
                e.x = __builtin_amdgcn_exp2f(acc[2 * q]);
                e.y = __builtin_amdgcn_exp2f(acc[2 * q + 1]);
                // packed accumulate: one VOP3P issue for two f32 adds
                asm("v_pk_add_f32 %0, %0, %1" : "+v"(sp[q]) : "v"(e));
            }
        }
    };

    // ---- pipelined schedule: only 2 barriers in the main body ----
    stage_half(0);
    __syncthreads();            // BF[0] + AF + NM ready

    af = *(const bf16x8*)&AF[g][lane];
    #pragma unroll
    for (int r = 0; r < 16; ++r) {
        const int row = (r & 3) + 8 * (r >> 2) + 4 * khalf;
        nmv[r] = NM[g * 32 + row];
    }

    stage_half(1);              // into BF[1]: no WAR hazard, overlaps compute
    compute_half(0);
    __syncthreads();            // BF[1] ready (and all BF[0] reads retired)
    compute_half(1);

    // ---- transposed reduction: spill per-lane partials into BF[0] space.
    // No barrier needed: BF[0] reads all completed before the last barrier;
    // other waves still in compute_half(1) only touch BF[1].
    // layout: SP[q*4+g][lane^((q&3)<<3)] as f32x2 (16 KB of BF[0]'s 32 KB).
    {
        f32x2* SP = (f32x2*)&BF[0][0][0];
        #pragma unroll
        for (int q = 0; q < 8; ++q)
            SP[(q * 4 + g) * 64 + (lane ^ ((q & 3) << 3))] = sp[q];
    }
    __syncthreads();

    // ---- gather epilogue: 2 threads per row sum 16 partials each + 1 shfl.
    {
        const float* SPf = (const float*)&BF[0][0][0];
        const int v  = threadIdx.x >> 1;        // row 0..127
        const int p  = threadIdx.x & 1;         // half of the 32 lane-partials
        const int gg = v >> 5, vv = v & 31;
        const int kh = (vv >> 2) & 1;           // lane-half holding this row
        const int r  = (vv & 3) | ((vv >> 3) << 2);  // acc reg index 0..15
        const int q  = r >> 1, comp = r & 1;
        const int sw = (q & 3) << 3;
        float val = 0.0f;
        #pragma unroll
        for (int jj = 0; jj < 16; ++jj) {
            const int j = (p * 16 + jj + v) & 31;   // rotate to spread banks
            const int l = kh * 32 + j;
            val += SPf[(((q * 4 + gg) * 64) + (l ^ sw)) * 2 + comp];
        }
        val += __shfl_xor(val, 1, 64);
        if (p == 0) {
            const int i = blockIdx.x * ROWS_PER_BLOCK + v;
            float oldv = first ? 0.0f : oldP[i];
            float res  = oldv - k2 * __log2f(val);
            outP[i] = avg ? 0.5f * (oldv + res) : res;
            if (last) NM[v] = res;   // stash for the output reduction
        }
    }

    // ---- last round: out[b] += sign * sum(res)/N, one atomic per block ----
    if (last) {
        __syncthreads();
        if (g == 0) {   // threads 0..63 re-reduce the 128 stashed values
            float v2 = NM[lane] + NM[64 + lane];
            #pragma unroll
            for (int off = 32; off >= 1; off >>= 1)
                v2 += __shfl_xor(v2, off, 64);
            if (lane == 0) {
                float sign = (type >= 2) ? -1.0f : 1.0f;   // f_aa,g_bb subtract
                atomicAdd(out + batch, sign * v2 * (1.0f / NPTS));
            }
        }
    }
}

extern "C" void kernel_launch(void* const* d_in, const int* in_sizes, int n_in,
                              void* d_out, int out_size, void* d_ws, size_t ws_size,
                              hipStream_t stream)
{
    const float* x = (const float*)d_in[0];
    const float* y = (const float*)d_in[1];
    float* out = (float*)d_out;

    // ws layout: P0, P1 (4 x B x NPTS floats each), then invariant arrays:
    // CF0 (2 x B x NPTS uint4), CF1 (uint2, .y holds ysq).
    const size_t potElems = (size_t)4 * BATCH * NPTS;
    const size_t colElems = (size_t)2 * BATCH * NPTS;
    float* P0  = (float*)d_ws;
    float* P1  = P0 + potElems;
    uint4* CF0 = (uint4*)(P1 + potElems);
    uint2* CF1 = (uint2*)(CF0 + colElems);
    // No P0 memset: round 0 (first=1) synthesizes zero potentials.

    // Zero the 8 output accumulators (harness poisons d_out each replay).
    hipMemsetAsync(out, 0, BATCH * sizeof(float), stream);

    // Epsilon schedule: [diam^p] + exp(arange(p ln diam, p ln blur, p ln scale)) + [blur^p]
    double epsl[16];
    int ne = 0;
    epsl[ne++] = 4.0;                       // diameter^2
    const double stop = 2.0 * log(0.05);
    const double step = 2.0 * log(0.5);
    for (double e = 2.0 * log(2.0); e > stop; e += step)
        epsl[ne++] = exp(e);                // 4, 1, 0.25, 0.0625, 0.015625, 0.00390625
    epsl[ne++] = 0.05 * 0.05;               // blur^2 = 0.0025

    float* src = P0;
    float* dst = P1;
    dim3 grid(NPTS / ROWS_PER_BLOCK, BATCH, 4);

    auto launch = [&](double eps, int avg, int first, int last) {
        float sigma  = (float)(M_LOG2E / eps);   // K=16, no k-dup
        float k2     = (float)(eps * M_LN2);
        float inv_k2 = (float)(1.0 / (eps * M_LN2));
        float rowc0  = (float)(eps * LOG_M);
        softmin_pass<<<grid, THREADS, 0, stream>>>(
            x, y, src, dst, CF0, CF1,
            sigma, k2, inv_k2, rowc0, avg, first, last, out);
        float* t = src; src = dst; dst = t;
    };

    launch(epsl[0], 0, 1, 0);                 // init (writes invariants)
    for (int k = 0; k < ne; ++k)
        launch(epsl[k], 1, 0, 0);             // damped symmetric Sinkhorn
    launch(epsl[ne - 1], 0, 0, 1);            // final extrapolation + output
}

// Round 6
// 233.660 us; speedup vs baseline: 1.0343x; 1.0045x over previous
//
#include <hip/hip_runtime.h>
#include <math.h>

// Problem constants (B=8 batches, N=M=2048 points, D=3)
#define BATCH 8
#define NPTS 2048
#define THREADS 256            // 4 waves = 4 row-groups of 32 rows
#define HALF_COLS 1024         // columns staged per LDS stage
#define TILES_H 32             // 32-col MFMA tiles per staged half
#define ROWS_PER_BLOCK 128     // 4 row-groups of 32
#define LOG_M 7.62559580411076 // log(2048)

typedef __attribute__((ext_vector_type(8)))  __bf16 bf16x8;
typedef __attribute__((ext_vector_type(16))) float  f32x16;
typedef __attribute__((ext_vector_type(2)))  float  f32x2;

union FragU { unsigned short u[8]; uint4 v; };

__device__ __forceinline__ unsigned short f2bf(float f) {
    union { float f; unsigned u; } x; x.f = f;
    unsigned r = x.u + 0x7FFFu + ((x.u >> 16) & 1u);   // RNE
    return (unsigned short)(r >> 16);
}
__device__ __forceinline__ float bf2f(unsigned short b) {
    union { unsigned u; float f; } x; x.u = ((unsigned)b) << 16;
    return x.f;
}

// Single-pass softmin via 32x32x16 MFMA with estimated LSE shift (no max pass).
//   arg_ij = (x'_i . y'_j + pot_j - 0.5|y'_j|^2) * log2(e)/eps  (log2 domain)
// K=16 slots: per dim, (xh,xh,xl,xl)x(yh,yl,yh,yl) = 4 products (12 slots),
// 3-way split of sigma*hhe vs 1.0 (3 slots), slot 15 zero; sigma=log2e/eps.
// Shift m2_hat = (rowconst - old)/k2 enters as the MFMA C operand;
// res = old - k2*log2(s) (rowconst cancels).
// This is the r19 kernel verbatim — the measured optimum of this design
// space (231.3 us). Full falsification record (r7-r17 prior session,
// r18-r22 this session):
//  r7  launch_bounds(512,4) pipeline: scratch spill
//  r10 hybrid poly-exp2 on VALU: worse (v_exp_f32 BLOCKS the SIMD issue
//      port ~16 cyc/wave-op; poly ~14 cyc/pair no better). Calibrated by
//      r18/r19: removed non-exp issue-slots convert ~0.9:1 to cycles.
//  r11/r12 single-kernel fusion: grid-barrier + fences cost ~28-100us/round
//      vs ~3us launch gaps
//  r13 triangle/mirror transpose identity: mirror scatter + imbalance
//  r15 32-row blocks at 2/CU: staging doubles, barriers 4x
//  r17 manual MFMA->exp2 pipeline: defeats compiler scheduling (261->279)
//  r18 (WIN -5.6us): v_pk_add_f32 accumulate + transposed-LDS-spill
//      reduction replacing the 5-step x16-reg shfl butterfly
//  r19 (WIN -24.7us): 128-row blocks halve staging+ramp; ysq in CF1.y [231.3]
//  r20/r21 (LOSS +10.3/+8.6): colsum transpose identity exact (absmax 0.0
//      through 8-launch G/R chain) but schedule-falsified at 2/CU (tail
//      generation) and 3/CU (staging:compute doubles at 64-row blocks)
//  r22 (LOSS +3.4): double-buffered B-staging — staging latency was ALREADY
//      hidden by block-level TLP; interleaving put staging issue 1:1 onto
//      the exp-blocked port
// Structural floor: ~13.7us/launch v_exp_f32 issue (2048 wave-exps/SIMD x
// ~16cyc) + ~1.5us non-exp issue + ~3us launch/ramp. Beating ~231us needs
// a sorted/pruned algorithm (Morton tile-skip is vacuous on unsorted
// uniform points) or a trans pipe that doesn't block wave issue.
// A/B layout: m(n)=lane&31, k=(lane>>5)*8+j.
// C/D layout (verified m74/m101): col=lane&31, row=(reg&3)+8*(reg>>2)+4*(lane>>5).
__global__ __launch_bounds__(THREADS, 2) void softmin_pass(
    const float* __restrict__ x, const float* __restrict__ y,
    const float* __restrict__ potSrc, float* __restrict__ potDst,
    uint4* __restrict__ CF0, uint2* __restrict__ CF1,
    float sigma, float k2, float inv_k2, float rowc0,
    int avg, int first, int last, float* __restrict__ out)
{
    __shared__ uint4 BF[TILES_H][64];     // 32 KB: B frags (one half), slot=lane
    __shared__ uint4 AF[4][64];           //  4 KB: A frags (4 row-groups)
    __shared__ float NM[ROWS_PER_BLOCK];  // -m2_hat per row; res stash on last

    const int type  = blockIdx.z;
    const int batch = blockIdx.y;

    const float* rowP;
    const float* colP;
    int hslot, oslot, cs;
    if (type == 0)      { rowP = x; colP = y; hslot = 1; oslot = 0; cs = 1; }  // f_ba
    else if (type == 1) { rowP = y; colP = x; hslot = 0; oslot = 1; cs = 0; }  // g_ab
    else if (type == 2) { rowP = x; colP = x; hslot = 2; oslot = 2; cs = 0; }  // f_aa
    else                { rowP = y; colP = y; hslot = 3; oslot = 3; cs = 1; }  // g_bb

    rowP += batch * NPTS * 3;
    colP += batch * NPTS * 3;
    const float* hP   = potSrc + (hslot * BATCH + batch) * NPTS;
    const float* oldP = potSrc + (oslot * BATCH + batch) * NPTS;
    float*       outP = potDst + (oslot * BATCH + batch) * NPTS;
    const size_t cbase = ((size_t)cs * BATCH + batch) * NPTS;

    // ---- stage A fragments: 4 groups x 64 slots = all 256 threads ----
    {
        const int gg = threadIdx.x >> 6, idx = threadIdx.x & 63;
        const int row = blockIdx.x * ROWS_PER_BLOCK + gg * 32 + (idx & 31);
        float x0 = rowP[3 * row + 0], x1 = rowP[3 * row + 1], x2 = rowP[3 * row + 2];
        float p0 = sigma * (x0 - 0.5f), p1 = sigma * (x1 - 0.5f), p2 = sigma * (x2 - 0.5f);
        unsigned short h0 = f2bf(p0); unsigned short l0 = f2bf(p0 - bf2f(h0));
        unsigned short h1 = f2bf(p1); unsigned short l1 = f2bf(p1 - bf2f(h1));
        unsigned short h2 = f2bf(p2); unsigned short l2 = f2bf(p2 - bf2f(h2));
        FragU f;
        if (idx < 32) {   // k0-7: dim0 (xh,xh,xl,xl), dim1 (xh,xh,xl,xl)
            f.u[0] = h0; f.u[1] = h0; f.u[2] = l0; f.u[3] = l0;
            f.u[4] = h1; f.u[5] = h1; f.u[6] = l1; f.u[7] = l1;
        } else {          // k8-15: dim2 (xh,xh,xl,xl), 1,1,1, 0
            f.u[0] = h2; f.u[1] = h2; f.u[2] = l2; f.u[3] = l2;
            f.u[4] = 0x3F80; f.u[5] = 0x3F80; f.u[6] = 0x3F80; f.u[7] = 0;
        }
        AF[gg][idx] = f.v;
    }
    if (threadIdx.x < ROWS_PER_BLOCK) {
        // ---- per-row shift: NM[r] = (old - rowconst)/k2 = -m2_hat ----
        const int r = threadIdx.x;
        const int i = blockIdx.x * ROWS_PER_BLOCK + r;
        float x0 = rowP[3 * i + 0], x1 = rowP[3 * i + 1], x2 = rowP[3 * i + 2];
        float p0 = x0 - 0.5f, p1 = x1 - 0.5f, p2 = x2 - 0.5f;
        float rowconst = 0.5f * (p0 * p0 + p1 * p1 + p2 * p2) + rowc0;
        float oldv = first ? 0.0f : oldP[i];
        NM[r] = (oldv - rowconst) * inv_k2;
    }

    const int lane = threadIdx.x & 63;
    const int g    = threadIdx.x >> 6;   // wave index == row-group 0..3
    const int khalf = lane >> 5;

    // accumulator as 8 packed pairs: sp[q] = {s[2q], s[2q+1]}
    f32x2 sp[8];
    #pragma unroll
    for (int q = 0; q < 8; ++q) { sp[q].x = 0.0f; sp[q].y = 0.0f; }
    bf16x8 af;
    f32x16 nmv;

    // ---- two column halves, BF restaged between them ----
    for (int h = 0; h < 2; ++h) {
        if (h) __syncthreads();   // all waves done reading previous half

        if (first) {
            // slow path: full recompute from coords (pot == 0); the writer
            // block of each (colset,batch) also stores the invariants.
            const int writer = (blockIdx.x == 0) && (type <= 1);
            for (int jj = threadIdx.x; jj < HALF_COLS; jj += THREADS) {
                const int j = h * HALF_COLS + jj;
                float y0 = colP[3 * j + 0], y1 = colP[3 * j + 1], y2 = colP[3 * j + 2];
                float p0 = y0 - 0.5f, p1 = y1 - 0.5f, p2 = y2 - 0.5f;
                unsigned short h0 = f2bf(p0); unsigned short l0 = f2bf(p0 - bf2f(h0));
                unsigned short h1 = f2bf(p1); unsigned short l1 = f2bf(p1 - bf2f(h1));
                unsigned short h2 = f2bf(p2); unsigned short l2 = f2bf(p2 - bf2f(h2));
                float ysq = 0.5f * (p0 * p0 + p1 * p1 + p2 * p2);
                float hhe = -sigma * ysq;                    // pot == 0
                unsigned short hA = f2bf(hhe); float r1 = hhe - bf2f(hA);
                unsigned short hB = f2bf(r1);  float r2 = r1 - bf2f(hB);
                unsigned short hC = f2bf(r2);
                FragU f0, f1;
                // k0-7: dim0 (yh,yl,yh,yl), dim1 (yh,yl,yh,yl)
                f0.u[0] = h0; f0.u[1] = l0; f0.u[2] = h0; f0.u[3] = l0;
                f0.u[4] = h1; f0.u[5] = l1; f0.u[6] = h1; f0.u[7] = l1;
                // k8-15: dim2 (yh,yl,yh,yl), hA,hB,hC, 0
                f1.u[0] = h2; f1.u[1] = l2; f1.u[2] = h2; f1.u[3] = l2;
                f1.u[4] = hA; f1.u[5] = hB; f1.u[6] = hC; f1.u[7] = 0;
                BF[jj >> 5][jj & 31]        = f0.v;   // k0-7  (lanes 0-31)
                BF[jj >> 5][32 + (jj & 31)] = f1.v;   // k8-15 (lanes 32-63)
                if (writer) {
                    CF0[cbase + j] = f0.v;
                    // CF1.x = (h2,l2); CF1.y stores ysq (the old .y was a dup)
                    CF1[cbase + j] = make_uint2(f1.v.x, __float_as_uint(ysq));
                }
            }
        } else {
            // fast path: invariants from global (L2-hit), only hhe recomputed
            for (int jj = threadIdx.x; jj < HALF_COLS; jj += THREADS) {
                const int j = h * HALF_COLS + jj;
                uint4 f0  = CF0[cbase + j];
                uint2 f1l = CF1[cbase + j];
                float ysq = __uint_as_float(f1l.y);
                float hhe = sigma * (hP[j] - ysq);
                unsigned short hA = f2bf(hhe); float r1 = hhe - bf2f(hA);
                unsigned short hB = f2bf(r1);  float r2 = r1 - bf2f(hB);
                unsigned short hC = f2bf(r2);
                uint4 f1 = make_uint4(f1l.x, f1l.x,
                                      (unsigned)hA | ((unsigned)hB << 16),
                                      (unsigned)hC);
                BF[jj >> 5][jj & 31]        = f0;     // k0-7  (lanes 0-31)
                BF[jj >> 5][32 + (jj & 31)] = f1;     // k8-15 (lanes 32-63)
            }
        }
        __syncthreads();

        if (h == 0) {   // A-frags / NM ready after first barrier
            af = *(const bf16x8*)&AF[g][lane];
            #pragma unroll
            for (int r = 0; r < 16; ++r) {
                const int row = (r & 3) + 8 * (r >> 2) + 4 * khalf;
                nmv[r] = NM[g * 32 + row];
            }
        }

        // all 32 staged tiles for this wave's 32 rows
        #pragma unroll 2
        for (int t = 0; t < TILES_H; ++t) {
            bf16x8 bf = *(const bf16x8*)&BF[t][lane];
            f32x16 acc = __builtin_amdgcn_mfma_f32_32x32x16_bf16(af, bf, nmv, 0, 0, 0);
            #pragma unroll
            for (int q = 0; q < 8; ++q) {
                f32x2 e;
                e.x = __builtin_amdgcn_exp2f(acc[2 * q]);
                e.y = __builtin_amdgcn_exp2f(acc[2 * q + 1]);
                // packed accumulate: one VOP3P issue for two f32 adds
                asm("v_pk_add_f32 %0, %0, %1" : "+v"(sp[q]) : "v"(e));
            }
        }
    }

    // ---- transposed reduction: spill per-lane partials into dead BF space
    // layout: SP[q*4+g][lane^((q&3)<<3)] as f32x2 (16 KB of BF's 32 KB).
    // b64 writes are a permutation of a contiguous 512B block -> conflict-free;
    // the XOR spreads the gather-side banks.
    __syncthreads();          // all waves done reading BF tiles
    {
        f32x2* SP = (f32x2*)&BF[0][0];
        #pragma unroll
        for (int q = 0; q < 8; ++q)
            SP[(q * 4 + g) * 64 + (lane ^ ((q & 3) << 3))] = sp[q];
    }
    __syncthreads();

    // ---- gather epilogue: 2 threads per row sum 16 partials each + 1 shfl.
    {
        const float* SPf = (const float*)&BF[0][0];
        const int v  = threadIdx.x >> 1;        // row 0..127
        const int p  = threadIdx.x & 1;         // half of the 32 lane-partials
        const int gg = v >> 5, vv = v & 31;
        const int kh = (vv >> 2) & 1;           // lane-half holding this row
        const int r  = (vv & 3) | ((vv >> 3) << 2);  // acc reg index 0..15
        const int q  = r >> 1, comp = r & 1;
        const int sw = (q & 3) << 3;
        float val = 0.0f;
        #pragma unroll
        for (int jj = 0; jj < 16; ++jj) {
            const int j = (p * 16 + jj + v) & 31;   // rotate to spread banks
            const int l = kh * 32 + j;
            val += SPf[(((q * 4 + gg) * 64) + (l ^ sw)) * 2 + comp];
        }
        val += __shfl_xor(val, 1, 64);
        if (p == 0) {
            const int i = blockIdx.x * ROWS_PER_BLOCK + v;
            float oldv = first ? 0.0f : oldP[i];
            float res  = oldv - k2 * __log2f(val);
            outP[i] = avg ? 0.5f * (oldv + res) : res;
            if (last) NM[v] = res;   // stash for the output reduction
        }
    }

    // ---- last round: out[b] += sign * sum(res)/N, one atomic per block ----
    if (last) {
        __syncthreads();
        if (g == 0) {   // threads 0..63 re-reduce the 128 stashed values
            float v2 = NM[lane] + NM[64 + lane];
            #pragma unroll
            for (int off = 32; off >= 1; off >>= 1)
                v2 += __shfl_xor(v2, off, 64);
            if (lane == 0) {
                float sign = (type >= 2) ? -1.0f : 1.0f;   // f_aa,g_bb subtract
                atomicAdd(out + batch, sign * v2 * (1.0f / NPTS));
            }
        }
    }
}

extern "C" void kernel_launch(void* const* d_in, const int* in_sizes, int n_in,
                              void* d_out, int out_size, void* d_ws, size_t ws_size,
                              hipStream_t stream)
{
    const float* x = (const float*)d_in[0];
    const float* y = (const float*)d_in[1];
    float* out = (float*)d_out;

    // ws layout: P0, P1 (4 x B x NPTS floats each), then invariant arrays:
    // CF0 (2 x B x NPTS uint4), CF1 (uint2, .y holds ysq).
    const size_t potElems = (size_t)4 * BATCH * NPTS;
    const size_t colElems = (size_t)2 * BATCH * NPTS;
    float* P0  = (float*)d_ws;
    float* P1  = P0 + potElems;
    uint4* CF0 = (uint4*)(P1 + potElems);
    uint2* CF1 = (uint2*)(CF0 + colElems);
    // No P0 memset: round 0 (first=1) synthesizes zero potentials.

    // Zero the 8 output accumulators (harness poisons d_out each replay).
    hipMemsetAsync(out, 0, BATCH * sizeof(float), stream);

    // Epsilon schedule: [diam^p] + exp(arange(p ln diam, p ln blur, p ln scale)) + [blur^p]
    double epsl[16];
    int ne = 0;
    epsl[ne++] = 4.0;                       // diameter^2
    const double stop = 2.0 * log(0.05);
    const double step = 2.0 * log(0.5);
    for (double e = 2.0 * log(2.0); e > stop; e += step)
        epsl[ne++] = exp(e);                // 4, 1, 0.25, 0.0625, 0.015625, 0.00390625
    epsl[ne++] = 0.05 * 0.05;               // blur^2 = 0.0025

    float* src = P0;
    float* dst = P1;
    dim3 grid(NPTS / ROWS_PER_BLOCK, BATCH, 4);

    auto launch = [&](double eps, int avg, int first, int last) {
        float sigma  = (float)(M_LOG2E / eps);   // K=16, no k-dup
        float k2     = (float)(eps * M_LN2);
        float inv_k2 = (float)(1.0 / (eps * M_LN2));
        float rowc0  = (float)(eps * LOG_M);
        softmin_pass<<<grid, THREADS, 0, stream>>>(
            x, y, src, dst, CF0, CF1,
            sigma, k2, inv_k2, rowc0, avg, first, last, out);
        float* t = src; src = dst; dst = t;
    };

    launch(epsl[0], 0, 1, 0);                 // init (writes invariants)
    for (int k = 0; k < ne; ++k)
        launch(epsl[k], 1, 0, 0);             // damped symmetric Sinkhorn
    launch(epsl[ne - 1], 0, 0, 1);            // final extrapolation + output
}